// Round 1
// baseline (661.685 us; speedup 1.0000x reference)
//
#include <hip/hip_runtime.h>
#include <hip/hip_bf16.h>

// Problem constants (fixed by the reference):
#define E_EDGES 640000
#define DIM     128
#define N_NODES 40000

typedef __bf16 bf16x8 __attribute__((ext_vector_type(8)));
typedef float  floatx4 __attribute__((ext_vector_type(4)));

// ---------------------------------------------------------------------------
// K1: zero the per-node edge counters + swizzle W (fp32 [128][128], W[f][d])
// into bf16 B-fragment lane order (identical layout to the verified kernel):
//   Wsw[((nb*4+kb)*64 + lane)*8 + j] = W[nb*16 + (lane&15)][kb*32 + (lane>>4)*8 + j]
// ---------------------------------------------------------------------------
__global__ void prep_kernel(const float* __restrict__ W,
                            __bf16* __restrict__ Wsw,
                            int* __restrict__ cnt) {
    int tid = blockIdx.x * blockDim.x + threadIdx.x;
    if (tid < N_NODES) cnt[tid] = 0;
    if (tid < 2048) {
        int lane = tid & 63;
        int kb   = (tid >> 6) & 3;
        int nb   = tid >> 8;
        int f    = nb * 16 + (lane & 15);
        int k0   = kb * 32 + ((lane >> 4) & 3) * 8;
        const float* wrow = W + f * DIM + k0;
        __bf16* o = Wsw + tid * 8;
#pragma unroll
        for (int j = 0; j < 8; ++j) o[j] = (__bf16)wrow[j];
    }
}

// K2: histogram of destination nodes. E = 640000 = 2500 * 256 exactly.
__global__ void hist_kernel(const int* __restrict__ dst, int* __restrict__ cnt) {
    int e = blockIdx.x * 256 + threadIdx.x;
    atomicAdd(&cnt[dst[e]], 1);
}

// K3: exclusive prefix scan of cnt[40000] -> starts[40000]. Single block,
// 1024 threads x 40 elements each (40960 >= 40000).
__global__ __launch_bounds__(1024)
void scan_kernel(const int* __restrict__ cnt, int* __restrict__ starts) {
    __shared__ int ssum[1024];
    const int t = threadIdx.x;
    const int base = t * 40;
    int local = 0;
#pragma unroll 4
    for (int i = 0; i < 40; ++i) {
        int idx = base + i;
        if (idx < N_NODES) local += cnt[idx];
    }
    ssum[t] = local;
    __syncthreads();
    // Hillis-Steele inclusive scan over 1024 partials (read, sync, write, sync)
    for (int off = 1; off < 1024; off <<= 1) {
        int v = (t >= off) ? ssum[t - off] : 0;
        __syncthreads();
        ssum[t] += v;
        __syncthreads();
    }
    int run = ssum[t] - local;  // exclusive prefix at this thread's chunk start
    for (int i = 0; i < 40; ++i) {
        int idx = base + i;
        if (idx < N_NODES) { starts[idx] = run; run += cnt[idx]; }
    }
}

// K4: scatter edge ids into per-node contiguous runs. After this kernel,
// starts[n] has been bumped to the END of node n's run (main kernel recovers
// the start as ends[n] - cnt[n]). Order within a run is nondeterministic,
// but max-reduction is order-invariant.
__global__ void scatter_kernel(const int* __restrict__ dst,
                               int* __restrict__ starts,
                               int* __restrict__ perm) {
    int e = blockIdx.x * 256 + threadIdx.x;
    int pos = atomicAdd(&starts[dst[e]], 1);
    perm[pos] = e;
}

// ---------------------------------------------------------------------------
// K5: one wave per destination node. Loop the node's edges in 16-row chunks:
//   chunk msg = src[perm-rows] @ W^T via 4 kblocks x 8 nblocks of
//   mfma_f32_16x16x32_bf16; running elementwise max across chunks in regs
//   (padded rows masked to -inf); final cross-row reduce (4 regs + 2 shfl_xor),
//   then out = relu(max + bias) written with ONE coalesced store pair.
//   Zero atomics. Empty nodes write -inf (matches jax segment_max).
// A-frag:  A[m=lane&15][k=q*8+j]   (gathered row, 16B loads)
// B-frag:  B[k=q*8+j][n=lane&15]   (pre-swizzled, staged in LDS per block)
// C/D:     col=lane&15, row=q*4+reg
// ---------------------------------------------------------------------------
__global__ __launch_bounds__(256)
void node_gemm_kernel(const float* __restrict__ src,
                      const __bf16* __restrict__ Wsw,
                      const float* __restrict__ bias,
                      const int* __restrict__ perm,
                      const int* __restrict__ cnt,
                      const int* __restrict__ ends,
                      float* __restrict__ out) {
    __shared__ bf16x8 Wl[2048];   // 32 KB swizzled W, shared by 4 waves
    const int t = threadIdx.x;
    {
        const float4* gw = (const float4*)Wsw;
        float4* lw = (float4*)Wl;
#pragma unroll
        for (int i = 0; i < 8; ++i) lw[t + i * 256] = gw[t + i * 256];
    }
    __syncthreads();

    const int lane = t & 63;
    const int wave = t >> 6;
    const int q    = lane >> 4;
    const int n    = lane & 15;
    const int node = blockIdx.x * 4 + wave;

    const int c     = cnt[node];
    const int start = ends[node] - c;
    float* orow = out + (size_t)node * DIM;

    if (c == 0) {   // empty segment: -inf, matching jax segment_max
        orow[lane]      = -INFINITY;
        orow[lane + 64] = -INFINITY;
        return;
    }

    floatx4 vmax[8];
#pragma unroll
    for (int nb = 0; nb < 8; ++nb) vmax[nb] = (floatx4)(-INFINITY);

    const int nch = (c + 15) >> 4;
    for (int ch = 0; ch < nch; ++ch) {
        int rows = c - (ch << 4);
        if (rows > 16) rows = 16;
        // row m = n of this chunk; all 4 q-lanes of a row fetch the same id
        int e = (n < rows) ? perm[start + (ch << 4) + n] : 0;
        const float* arow = src + (size_t)e * DIM + q * 8;

        floatx4 acc[8];
#pragma unroll
        for (int nb = 0; nb < 8; ++nb) acc[nb] = (floatx4)(0.0f);

#pragma unroll
        for (int kb = 0; kb < 4; ++kb) {
            float4 a0 = *(const float4*)(arow + kb * 32);
            float4 a1 = *(const float4*)(arow + kb * 32 + 4);
            bf16x8 af;
            af[0] = (__bf16)a0.x; af[1] = (__bf16)a0.y;
            af[2] = (__bf16)a0.z; af[3] = (__bf16)a0.w;
            af[4] = (__bf16)a1.x; af[5] = (__bf16)a1.y;
            af[6] = (__bf16)a1.z; af[7] = (__bf16)a1.w;
#pragma unroll
            for (int nb = 0; nb < 8; ++nb) {
                bf16x8 bf = Wl[(nb * 4 + kb) * 64 + lane];
                acc[nb] = __builtin_amdgcn_mfma_f32_16x16x32_bf16(af, bf, acc[nb], 0, 0, 0);
            }
        }

        // running max; rows beyond this chunk's valid count masked to -inf
#pragma unroll
        for (int nb = 0; nb < 8; ++nb) {
#pragma unroll
            for (int r = 0; r < 4; ++r) {
                float v = (q * 4 + r < rows) ? acc[nb][r] : -INFINITY;
                vmax[nb][r] = fmaxf(vmax[nb][r], v);
            }
        }
    }

    // reduce the 16 row-slots per column: 4 regs locally + q-groups via shfl
    float red[8];
#pragma unroll
    for (int nb = 0; nb < 8; ++nb) {
        float v = fmaxf(fmaxf(vmax[nb][0], vmax[nb][1]),
                        fmaxf(vmax[nb][2], vmax[nb][3]));
        v = fmaxf(v, __shfl_xor(v, 16));
        v = fmaxf(v, __shfl_xor(v, 32));
        red[nb] = v;   // column max for col = nb*16 + n (all lanes)
    }

    // lane writes col = lane (nb = q) and col = lane+64 (nb = q+4):
    // compile-time-indexed selects (no scratch), fully coalesced 256B stores
    float o1 = (q == 0) ? red[0] : (q == 1) ? red[1] : (q == 2) ? red[2] : red[3];
    float o2 = (q == 0) ? red[4] : (q == 1) ? red[5] : (q == 2) ? red[6] : red[7];

    // bias-add and relu commute with max (bias is per-column, relu monotone)
    orow[lane]      = fmaxf(o1 + bias[lane],      0.0f);
    orow[lane + 64] = fmaxf(o2 + bias[lane + 64], 0.0f);
}

extern "C" void kernel_launch(void* const* d_in, const int* in_sizes, int n_in,
                              void* d_out, int out_size, void* d_ws, size_t ws_size,
                              hipStream_t stream) {
    const float* src  = (const float*)d_in[0];
    const float* W    = (const float*)d_in[1];
    const float* bias = (const float*)d_in[2];
    const int*   dst  = (const int*)d_in[3];
    // d_in[4] = n_nodes (scalar) — compile-time constant here.

    // workspace layout (total ~2.92 MB):
    char* ws = (char*)d_ws;
    __bf16* Wsw  = (__bf16*)ws;                      // 32768 B
    int* cnt     = (int*)(ws + 32768);               // 160000 B
    int* starts  = (int*)(ws + 32768 + 160000);      // 160000 B
    int* perm    = (int*)(ws + 32768 + 320000);      // 2560000 B
    float* outf  = (float*)d_out;

    // K1: zero cnt + swizzle W  (40192 threads covers both ranges)
    prep_kernel<<<(N_NODES + 255) / 256, 256, 0, stream>>>(W, Wsw, cnt);
    // K2: per-node edge histogram
    hist_kernel<<<E_EDGES / 256, 256, 0, stream>>>(dst, cnt);
    // K3: exclusive scan -> starts
    scan_kernel<<<1, 1024, 0, stream>>>(cnt, starts);
    // K4: scatter edge ids into contiguous per-node runs (starts -> ends)
    scatter_kernel<<<E_EDGES / 256, 256, 0, stream>>>(dst, starts, perm);
    // K5: one wave per node, atomic-free GEMM + segmented max
    node_gemm_kernel<<<N_NODES / 4, 256, 0, stream>>>(src, Wsw, bias, perm,
                                                      cnt, starts, outf);
}